// Round 10
// baseline (5397.868 us; speedup 1.0000x reference)
//
#include <hip/hip_runtime.h>

#define B_ 256
#define T_ 128
#define V_ 42
#define LAT_ 200
#define U_ 512
#define G4_ 2048
#define NBLK 196
// one flag per 64B cache line: FI gives the base int-index of a 32-flag group
#define FI(r, m) ((((r) * 2) + (m)) * 32 * 16)
#define SLOT_ ((size_t)B_ * U_)          // 131072 ushorts per (layer,t) slot
#define LS_ ((size_t)129 * SLOT_)        // layer stride: 129 write-once slots

typedef unsigned short ushort_t;
typedef __attribute__((ext_vector_type(8))) short bf8;
typedef __attribute__((ext_vector_type(4))) float f4;

__device__ __forceinline__ ushort_t f2bf(float f) {
  union { float f; unsigned int i; } v; v.f = f;
  unsigned int r = v.i + 0x7fffu + ((v.i >> 16) & 1u);
  return (ushort_t)(r >> 16);
}
__device__ __forceinline__ float sigf(float x) { return 1.f / (1.f + __expf(-x)); }
__device__ __forceinline__ float tanhfast(float x) {
  float e = __expf(2.f * x);
  return 1.f - 2.f / (e + 1.f);
}
__device__ __forceinline__ void wait_vm0() {
  asm volatile("s_waitcnt vmcnt(0)" ::: "memory");
}
// ---- MALL-coherent write-through stores (R4/R7-proven) ----
__device__ __forceinline__ void st_wt_b16(void* p, ushort_t v) {
  unsigned int vv = v;
  asm volatile("global_store_short %0, %1, off sc0 sc1" :: "v"(p), "v"(vv) : "memory");
}

// table[v][j] = sum_n emb[v,n] * k0[roff+n][j]
__global__ __launch_bounds__(256) void table_kernel(const float* emb, const float* k0, int roff, float* table) {
  int v = blockIdx.x, tid = threadIdx.x;
  __shared__ float e[LAT_];
  for (int i = tid; i < LAT_; i += 256) e[i] = emb[v * LAT_ + i];
  __syncthreads();
  for (int j = tid; j < G4_; j += 256) {
    float s = 0.f;
    for (int n = 0; n < LAT_; n++) s += e[n] * k0[(size_t)(roff + n) * G4_ + j];
    table[v * G4_ + j] = s;
  }
}

// ---------------------------------------------------------------------------
// Swizzled-weight layout per matrix: [nt16][kt][lane][8] bf16.
// Mats: 0=encL0ext(KT18) 1=decL0ext(KT26) 2..5=encK1,R1,K2,R2 6..9=dec...
// 10=Wo (3 nt16, KT16, 48 cols padded).
// ---------------------------------------------------------------------------
__device__ __forceinline__ size_t mat_off_u4(int m) {
  if (m == 0) return 0;
  if (m == 1) return 147456;
  if (m < 10) return 360448 + (size_t)(m - 2) * 131072;
  return 1409024;
}

struct SwzSrc {
  const float *enc_rk0, *enc_k0, *enc_b0;
  const float *dec_rk0, *dec_k0, *dec_b0;
  const float *tabE, *tabD;
  const float *encK1, *encR1, *encK2, *encR2;
  const float *decK1, *decR1, *decK2, *decR2;
  const float *Wo;
  ushort_t* dst;
};

__device__ float swz_val(const SwzSrc& s, int mat, int k, int n) {
  switch (mat) {
    case 0: {
      if (k < 512) return s.enc_rk0[(size_t)k * G4_ + n];
      int i = k - 512;
      if (i < 42) return s.tabE[(size_t)i * G4_ + n];
      if (i < 45) return s.enc_k0[(size_t)(200 + i - 42) * G4_ + n];
      if (i == 45) return s.enc_b0[n];
      return 0.f;
    }
    case 1: {
      if (k < 512) return s.dec_rk0[(size_t)k * G4_ + n];
      int i = k - 512;
      if (i < 200) return s.dec_k0[(size_t)i * G4_ + n];
      if (i < 256) return 0.f;
      i -= 256;
      if (i < 42) return s.tabD[(size_t)i * G4_ + n];
      if (i < 45) return s.dec_k0[(size_t)(400 + i - 42) * G4_ + n];
      if (i == 45) return s.dec_b0[n];
      return 0.f;
    }
    case 2: return s.encK1[(size_t)k * G4_ + n];
    case 3: return s.encR1[(size_t)k * G4_ + n];
    case 4: return s.encK2[(size_t)k * G4_ + n];
    case 5: return s.encR2[(size_t)k * G4_ + n];
    case 6: return s.decK1[(size_t)k * G4_ + n];
    case 7: return s.decR1[(size_t)k * G4_ + n];
    case 8: return s.decK2[(size_t)k * G4_ + n];
    case 9: return s.decR2[(size_t)k * G4_ + n];
    default: return (n < V_) ? s.Wo[(size_t)k * V_ + n] : 0.f;
  }
}

__global__ __launch_bounds__(256) void swz_ext_kernel(SwzSrc s) {
  int b = blockIdx.x, tid = threadIdx.x;
  int mat, nt16;
  if (b < 1280) { mat = b >> 7; nt16 = b & 127; } else { mat = 10; nt16 = b - 1280; }
  int ktMax = (mat == 0) ? 18 : (mat == 1) ? 26 : 16;
  int lane = tid & 63, l15 = lane & 15, q = lane >> 4;
  int n = nt16 * 16 + l15;
  uint4* dst = (uint4*)s.dst;
  size_t off = mat_off_u4(mat);
  for (int kt = tid >> 6; kt < ktMax; kt += 4) {
    ushort_t o[8];
    int kb = kt * 32 + q * 8;
#pragma unroll
    for (int j = 0; j < 8; j++) o[j] = f2bf(swz_val(s, mat, kb + j, n));
    dst[off + ((size_t)nt16 * ktMax + kt) * 64 + lane] = *(const uint4*)o;
  }
}

// ---------------------------------------------------------------------------
struct PP {
  const ushort_t* swz;
  ushort_t* ring;                 // write-once h: [3 layers][129 slots][B][U] bf16
  float* c2g; ushort_t* zf16; float* sums; int* bar; int* gen; int* flg; float* out;
  const float *enc_b1, *enc_b2, *dec_b1, *dec_b2;
  const float *Wm, *bm, *Ws, *bs, *eps, *C, *bo;
  const int *X, *Y, *Lb;
};

// Full grid barrier — phase boundaries only. All-thread rel/acq fences.
__device__ __forceinline__ void grid_barrier(int* bar, int* gen) {
  __builtin_amdgcn_fence(__ATOMIC_RELEASE, "agent");
  __syncthreads();
  if (threadIdx.x == 0) {
    int g = __hip_atomic_load(gen, __ATOMIC_RELAXED, __HIP_MEMORY_SCOPE_AGENT);
    if (__hip_atomic_fetch_add(bar, 1, __ATOMIC_ACQ_REL, __HIP_MEMORY_SCOPE_AGENT) == NBLK - 1) {
      __hip_atomic_store(bar, 0, __ATOMIC_RELAXED, __HIP_MEMORY_SCOPE_AGENT);
      __hip_atomic_store(gen, g + 1, __ATOMIC_RELEASE, __HIP_MEMORY_SCOPE_AGENT);
    } else {
      int gg;
      do {
        __builtin_amdgcn_s_sleep(8);
        gg = __hip_atomic_load(gen, __ATOMIC_ACQUIRE, __HIP_MEMORY_SCOPE_AGENT);
      } while (gg == g);
    }
  }
  __syncthreads();
  __builtin_amdgcn_fence(__ATOMIC_ACQUIRE, "agent");
}

// Line-distributed spin: flag i lives at f[i*16] (own 64B line). Lane i polls
// its own line — requests fan out across MALL slices, no same-line queueing.
__device__ __forceinline__ void wait_flags(const int* f, int cnt, int target) {
  int lane = threadIdx.x & 63;
  bool need = lane < cnt;
  const int* a = f + (need ? lane : 0) * 16;
  for (;;) {
    int v = __hip_atomic_load(a, __ATOMIC_RELAXED, __HIP_MEMORY_SCOPE_AGENT);
    bool bad = need && (v < target);
    if (__ballot(bad) == 0ull) return;
  }
}

#define MFMA(a, bfrag, c) __builtin_amdgcn_mfma_f32_16x16x32_bf16((a), (bfrag), (c), 0, 0, 0)

__global__ __launch_bounds__(256, 1) void persist(PP p) {
  __shared__ uint4 wlds4[8192];  // 128KB: weights + z-scratch + token caches
  const int b = blockIdx.x, tid = threadIdx.x;
  const int lane = tid & 63, w = tid >> 6, q = lane >> 4, l15 = lane & 15;
  const int role = b < 64 ? 0 : b < 128 ? 1 : b < 192 ? 2 : 3;
  const int idx = b & 63;
  const int ut = idx >> 1;
  const int mi = idx & 1;
  const int m0 = mi * 128;
  const int rw = m0 + w * 32;
  const int u = ut * 16 + l15;
  const uint4* swzU4 = (const uint4*)p.swz;
  const int cb = b - 192;

  unsigned char* tok = (unsigned char*)wlds4 + 106496;  // role0 X cache [128][133]
  unsigned char* ytok = (unsigned char*)wlds4 + 49152;  // CE Y cache [64][133]

  // layer-0 per-lane constants: C rows as bf16
  ushort_t cb0[2][3];
  if (role == 0) {
#pragma unroll
    for (int ms = 0; ms < 2; ms++)
#pragma unroll
      for (int j = 0; j < 3; j++) cb0[ms][j] = f2bf(p.C[(rw + ms * 16 + l15) * 3 + j]);
  }

  const int pubidx = FI(role, mi) + ut * 16;  // role<3 only; own 64B line

  float ce_local = 0.f;
  float boR0 = 0.f, boR1 = 0.f, boR2 = 0.f;
  int Lr[4] = {0, 0, 0, 0};
  int pub = 0;

  for (int phase = 0; phase < 2; phase++) {
    const bool dec = (phase == 1);

    if (dec) {
      grid_barrier(p.bar, p.gen);  // encoder fully done; c2g visible; ring lines invalidated
      if (b < 50) {
        // ---- VAE (blocks 0..49): z + KL ----
        int lat0 = b * 4;
        int row = tid;
        float m[4], ls[4];
#pragma unroll
        for (int lc = 0; lc < 4; lc++) { m[lc] = p.bm[lat0 + lc]; ls[lc] = p.bs[lat0 + lc]; }
        const float* cr = p.c2g + (size_t)row * U_;
        for (int k = 0; k < U_; k++) {
          float hv = cr[k];
#pragma unroll
          for (int lc = 0; lc < 4; lc++) {
            m[lc] += hv * p.Wm[k * LAT_ + lat0 + lc];
            ls[lc] += hv * p.Ws[k * LAT_ + lat0 + lc];
          }
        }
        float kl = 0.f;
#pragma unroll
        for (int lc = 0; lc < 4; lc++) {
          int lat = lat0 + lc;
          float zz = m[lc] + __expf(0.5f * ls[lc]) * p.eps[row * LAT_ + lat];
          p.zf16[row * 256 + lat] = f2bf(zz);
          kl += 1.f + ls[lc] - m[lc] * m[lc] - __expf(ls[lc]);
        }
        float* red = (float*)wlds4;
        red[tid] = kl; __syncthreads();
        for (int st = 128; st > 0; st >>= 1) { if (tid < st) red[tid] += red[tid + st]; __syncthreads(); }
        if (tid == 0) atomicAdd(p.sums + 1, red[0]);
      }
      __syncthreads();
    }

    // ---- stage weights (+ token caches) for this phase into LDS ----
    // role0 step layout (both phases): [g][kt 0..17][lane] with kt16..17 = const region.
    // decoder additionally stages z-weights (src kt16..23) at z-scratch u4[4608..6656).
    if (role == 0) {
      if (!dec) {
        size_t mo = mat_off_u4(0);
        for (int g = 0; g < 4; g++) {
          int nt16 = g * 32 + ut;
          size_t src = mo + (size_t)nt16 * 18 * 64;
          int dst = g * 18 * 64;
          for (int i = tid; i < 18 * 64; i += 256) wlds4[dst + i] = swzU4[src + i];
        }
        // X token cache (persists through both phases)
        for (int i = tid; i < 128 * T_; i += 256) {
          int r = i >> 7, t = i & 127;
          tok[r * 133 + t] = (unsigned char)p.X[(size_t)(m0 + r) * T_ + t];
        }
      } else {
        size_t mo = mat_off_u4(1);  // KT26 source layout
        for (int g = 0; g < 4; g++) {
          int nt16 = g * 32 + ut;
          size_t src = mo + (size_t)nt16 * 26 * 64;
          int dst = g * 18 * 64;
          for (int i = tid; i < 16 * 64; i += 256) wlds4[dst + i] = swzU4[src + i];               // rk0
          for (int i = tid; i < 2 * 64; i += 256) wlds4[dst + 16 * 64 + i] = swzU4[src + 24 * 64 + i];  // const
          for (int i = tid; i < 8 * 64; i += 256) wlds4[4608 + g * 512 + i] = swzU4[src + 16 * 64 + i]; // z
        }
      }
    } else if (role <= 2) {
      int matK = dec ? (role == 1 ? 6 : 8) : (role == 1 ? 2 : 4);
      for (int gm = 0; gm < 2; gm++) {
        size_t mo = mat_off_u4(matK + gm);
        for (int g = 0; g < 4; g++) {
          int nt16 = g * 32 + ut;
          size_t src = mo + (size_t)nt16 * 1024;
          int dst = gm * 4096 + g * 1024;
          for (int i = tid; i < 1024; i += 256) wlds4[dst + i] = swzU4[src + i];
        }
      }
    } else if (dec) {
      size_t mo = mat_off_u4(10);
      for (int i = tid; i < 3072; i += 256) wlds4[i] = swzU4[mo + i];
      for (int i = tid; i < 64 * T_; i += 256) {
        int r = i >> 7, t = i & 127;
        ytok[r * 133 + t] = (unsigned char)p.Y[(size_t)(cb * 64 + r) * T_ + t];
      }
      int r0c = cb * 64 + w * 16;
      boR0 = p.bo[l15]; boR1 = p.bo[16 + l15]; boR2 = (l15 < 10) ? p.bo[32 + l15] : 0.f;
#pragma unroll
      for (int r = 0; r < 4; r++) Lr[r] = p.Lb[r0c + q * 4 + r];
    }
    __syncthreads();

    // ---- per-phase register state ----
    float creg[2][4];
#pragma unroll
    for (int ms = 0; ms < 2; ms++)
#pragma unroll
      for (int r = 0; r < 4; r++) creg[ms][r] = 0.f;
    float bias[4] = {0.f, 0.f, 0.f, 0.f};
    if (role == 1 || role == 2) {
      const float* bb = dec ? (role == 1 ? p.dec_b1 : p.dec_b2) : (role == 1 ? p.enc_b1 : p.enc_b2);
#pragma unroll
      for (int g = 0; g < 4; g++) bias[g] = bb[g * 512 + u];
    }

    // ---- wait-sets (write-once ring: RAW deps only, no WAR) ----
    const int* myp = nullptr; int myc = 0;
    if (role == 0) {
      if (w == 0) { myp = p.flg + FI(0, mi); myc = 32; }
    } else if (role == 1) {
      if (w == 0) { myp = p.flg + FI(0, mi); myc = 32; }
      else if (w == 1) { myp = p.flg + FI(1, mi); myc = 32; }
    } else if (role == 2) {
      if (w == 0) { myp = p.flg + FI(1, mi); myc = 32; }
      else if (w == 1) { myp = p.flg + FI(2, mi); myc = 32; }
    } else {
      if (w == 0 && dec) { myp = p.flg + FI(2, cb >> 1); myc = 32; }
    }

    grid_barrier(p.bar, p.gen);  // phase aligned; zf16/weights visible

    // ---- per-phase accumulator init (zacc): decoder role0 folds the constant
    //      z-contribution here ONCE (8-kt MFMA vs z-scratch); else zero. ----
    f4 zacc[2][4];
#pragma unroll
    for (int ms = 0; ms < 2; ms++)
#pragma unroll
      for (int g = 0; g < 4; g++) zacc[ms][g] = (f4){0.f, 0.f, 0.f, 0.f};
    if (role == 0 && dec) {
      const ushort_t* Az0 = p.zf16 + (rw + l15) * 256 + q * 8;
#pragma unroll
      for (int kz = 0; kz < 8; kz++) {
        bf8 a0 = *(const bf8*)(Az0 + kz * 32);
        bf8 a1 = *(const bf8*)(Az0 + 16 * 256 + kz * 32);
#pragma unroll
        for (int g = 0; g < 4; g++) {
          bf8 bbf = *(const bf8*)&wlds4[4608 + g * 512 + kz * 64 + lane];
          zacc[0][g] = MFMA(a0, bbf, zacc[0][g]);
          zacc[1][g] = MFMA(a1, bbf, zacc[1][g]);
        }
      }
    }

    // ---- wavefront steps: flag-synced, fence-free, write-once slots ----
    const int smax = dec ? T_ + 3 : T_ + 2;
    for (int s = 0; s < smax; s++) {
      pub++;
      if (myc) wait_flags(myp, myc, pub - 1);
      __syncthreads();

      const int lag = (role <= 2) ? role : 3;
      const int t = s - lag;
      if (role == 3) {
        if (dec && t >= 0 && t < T_) {
          // ======== CE: logits GEMM + online softmax (h2[t] at slot t+1) ========
          int r0c = cb * 64 + w * 16;
          const ushort_t* Ar = p.ring + 2 * LS_ + (size_t)(t + 1) * SLOT_ + (size_t)(r0c + l15) * U_ + q * 8;
          f4 a3[3];
#pragma unroll
          for (int nt = 0; nt < 3; nt++) a3[nt] = (f4){0.f, 0.f, 0.f, 0.f};
#pragma unroll 4
          for (int kt = 0; kt < 16; kt++) {
            bf8 a = *(const bf8*)(Ar + kt * 32);
#pragma unroll
            for (int nt = 0; nt < 3; nt++) {
              bf8 bbf = *(const bf8*)&wlds4[nt * 1024 + kt * 64 + lane];
              a3[nt] = MFMA(a, bbf, a3[nt]);
            }
          }
#pragma unroll
          for (int r = 0; r < 4; r++) {
            float v0 = a3[0][r] + boR0;
            float v1 = a3[1][r] + boR1;
            float v2 = (l15 < 10) ? a3[2][r] + boR2 : -3.0e38f;
            float mx = fmaxf(fmaxf(v0, v1), v2);
            mx = fmaxf(mx, __shfl_xor(mx, 1)); mx = fmaxf(mx, __shfl_xor(mx, 2));
            mx = fmaxf(mx, __shfl_xor(mx, 4)); mx = fmaxf(mx, __shfl_xor(mx, 8));
            float se = __expf(v0 - mx) + __expf(v1 - mx) + ((l15 < 10) ? __expf(v2 - mx) : 0.f);
            int yv = ytok[(w * 16 + q * 4 + r) * 133 + t];
            float py = (l15 == yv ? v0 : 0.f) + (l15 + 16 == yv ? v1 : 0.f) + (l15 + 32 == yv ? v2 : 0.f);
            se += __shfl_xor(se, 1); se += __shfl_xor(se, 2); se += __shfl_xor(se, 4); se += __shfl_xor(se, 8);
            py += __shfl_xor(py, 1); py += __shfl_xor(py, 2); py += __shfl_xor(py, 4); py += __shfl_xor(py, 8);
            if (l15 == 0 && t < Lr[r]) ce_local += mx + __logf(se) - py;
          }
        }
      } else if (t >= 0 && t < T_) {
        // ======== LSTM layer step ========
        f4 acc[2][4];
#pragma unroll
        for (int ms = 0; ms < 2; ms++)
#pragma unroll
          for (int g = 0; g < 4; g++) acc[ms][g] = zacc[ms][g];

        const ushort_t* hin = p.ring + (size_t)role * LS_ + (size_t)t * SLOT_;        // h[t-1]
        ushort_t* hout = p.ring + (size_t)role * LS_ + (size_t)(t + 1) * SLOT_;       // h[t]
        const ushort_t* Ah0 = hin + (size_t)(rw + l15) * U_ + q * 8;
        const ushort_t* Ah1 = Ah0 + 16 * U_;

        if (role == 0) {
          const int KT64 = 18 * 64;
#pragma unroll 4
          for (int kt = 0; kt < 16; kt++) {
            bf8 a0 = *(const bf8*)(Ah0 + kt * 32);
            bf8 a1 = *(const bf8*)(Ah1 + kt * 32);
#pragma unroll
            for (int g = 0; g < 4; g++) {
              bf8 bbf = *(const bf8*)&wlds4[g * KT64 + kt * 64 + lane];
              acc[0][g] = MFMA(a0, bbf, acc[0][g]);
              acc[1][g] = MFMA(a1, bbf, acc[1][g]);
            }
          }
          // const region at kt 16..17 (one-hot token, C, 1)
          int xv0 = tok[(w * 32 + l15) * 133 + t];
          int xv1 = tok[(w * 32 + 16 + l15) * 133 + t];
#pragma unroll
          for (int ktc = 0; ktc < 2; ktc++) {
            union { ushort_t us[8]; bf8 v; } a0u, a1u;
#pragma unroll
            for (int j = 0; j < 8; j++) {
              int id = ktc * 32 + q * 8 + j;
              ushort_t v0 = (id == xv0) ? (ushort_t)0x3F80 : (ushort_t)0;
              ushort_t v1 = (id == xv1) ? (ushort_t)0x3F80 : (ushort_t)0;
              if (id >= 42 && id < 45) { v0 = cb0[0][id - 42]; v1 = cb0[1][id - 42]; }
              if (id == 45) { v0 = 0x3F80; v1 = 0x3F80; }
              a0u.us[j] = v0; a1u.us[j] = v1;
            }
            int kt = 16 + ktc;
#pragma unroll
            for (int g = 0; g < 4; g++) {
              bf8 bbf = *(const bf8*)&wlds4[g * KT64 + kt * 64 + lane];
              acc[0][g] = MFMA(a0u.v, bbf, acc[0][g]);
              acc[1][g] = MFMA(a1u.v, bbf, acc[1][g]);
            }
          }
        } else {
          const ushort_t* xin = p.ring + (size_t)(role - 1) * LS_ + (size_t)(t + 1) * SLOT_;  // h^{l-1}[t]
          const ushort_t* Ax0 = xin + (size_t)(rw + l15) * U_ + q * 8;
          const ushort_t* Ax1 = Ax0 + 16 * U_;
#pragma unroll 4
          for (int kt = 0; kt < 16; kt++) {
            bf8 a0 = *(const bf8*)(Ax0 + kt * 32);
            bf8 a1 = *(const bf8*)(Ax1 + kt * 32);
#pragma unroll
            for (int g = 0; g < 4; g++) {
              bf8 bbf = *(const bf8*)&wlds4[g * 1024 + kt * 64 + lane];
              acc[0][g] = MFMA(a0, bbf, acc[0][g]);
              acc[1][g] = MFMA(a1, bbf, acc[1][g]);
            }
          }
#pragma unroll 4
          for (int kt = 0; kt < 16; kt++) {
            bf8 a0 = *(const bf8*)(Ah0 + kt * 32);
            bf8 a1 = *(const bf8*)(Ah1 + kt * 32);
#pragma unroll
            for (int g = 0; g < 4; g++) {
              bf8 bbf = *(const bf8*)&wlds4[4096 + g * 1024 + kt * 64 + lane];
              acc[0][g] = MFMA(a0, bbf, acc[0][g]);
              acc[1][g] = MFMA(a1, bbf, acc[1][g]);
            }
          }
        }

        // ---- gate pointwise; h stores write-through sc0 sc1 ----
#pragma unroll
        for (int ms = 0; ms < 2; ms++)
#pragma unroll
          for (int r = 0; r < 4; r++) {
            int row = rw + ms * 16 + q * 4 + r;
            float zi = acc[ms][0][r] + bias[0];
            float zf = acc[ms][1][r] + bias[1];
            float zg = acc[ms][2][r] + bias[2];
            float zo = acc[ms][3][r] + bias[3];
            float cp = creg[ms][r];
            float cn = sigf(zf) * cp + sigf(zi) * tanhfast(zg);
            float hn = sigf(zo) * tanhfast(cn);
            creg[ms][r] = cn;
            st_wt_b16(&hout[(size_t)row * U_ + u], f2bf(hn));
            if (!dec && role == 2 && t == T_ - 1) p.c2g[(size_t)row * U_ + u] = cn;
          }
      }
      wait_vm0();        // all h stores ACKed at the MALL
      __syncthreads();   // ... for every wave of the block
      if (tid == 0 && role < 3)
        __hip_atomic_exchange(p.flg + pubidx, pub, __ATOMIC_RELAXED, __HIP_MEMORY_SCOPE_AGENT);
    }
  }

  // ---- CE flush, final reduce ----
  if (role == 3 && l15 == 0) atomicAdd(p.sums + 0, ce_local);
  grid_barrier(p.bar, p.gen);
  if (b == 0 && tid == 0) {
    float recon = p.sums[0] * (1.f / ((float)B_ * (float)T_));
    float latent = -0.5f * p.sums[1] * (1.f / ((float)B_ * (float)LAT_));
    p.out[0] = recon + latent;
    p.out[1] = recon;
    p.out[2] = latent;
  }
}

// ---------------------------------------------------------------------------
extern "C" void kernel_launch(void* const* d_in, const int* in_sizes, int n_in,
                              void* d_out, int out_size, void* d_ws, size_t ws_size,
                              hipStream_t stream) {
  const int*   X       = (const int*)d_in[0];
  const int*   Y       = (const int*)d_in[1];
  const float* C       = (const float*)d_in[2];
  const int*   L       = (const int*)d_in[3];
  const float* eps     = (const float*)d_in[4];
  const float* emb_enc = (const float*)d_in[5];
  const float* emb_dec = (const float*)d_in[6];
  const float* enc_k0  = (const float*)d_in[7];
  const float* enc_rk0 = (const float*)d_in[8];
  const float* enc_b0  = (const float*)d_in[9];
  const float* enc_k1  = (const float*)d_in[10];
  const float* enc_rk1 = (const float*)d_in[11];
  const float* enc_b1  = (const float*)d_in[12];
  const float* enc_k2  = (const float*)d_in[13];
  const float* enc_rk2 = (const float*)d_in[14];
  const float* enc_b2  = (const float*)d_in[15];
  const float* dec_k0  = (const float*)d_in[16];
  const float* dec_rk0 = (const float*)d_in[17];
  const float* dec_b0  = (const float*)d_in[18];
  const float* dec_k1  = (const float*)d_in[19];
  const float* dec_rk1 = (const float*)d_in[20];
  const float* dec_b1  = (const float*)d_in[21];
  const float* dec_k2  = (const float*)d_in[22];
  const float* dec_rk2 = (const float*)d_in[23];
  const float* dec_b2  = (const float*)d_in[24];
  const float* Wm      = (const float*)d_in[25];
  const float* bm      = (const float*)d_in[26];
  const float* Ws      = (const float*)d_in[27];
  const float* bs      = (const float*)d_in[28];
  const float* Wo      = (const float*)d_in[29];
  const float* bo      = (const float*)d_in[30];
  float* out = (float*)d_out;
  (void)in_sizes; (void)n_in; (void)out_size; (void)ws_size;

  char* wsb = (char*)d_ws;
  size_t o = 0;
  auto take = [&](size_t bytes) -> char* { char* p = wsb + o; o += (bytes + 255) & ~(size_t)255; return p; };

  // ---- small zeroed region ----
  float* c2g  = (float*)take((size_t)B_ * U_ * 4);
  ushort_t* zf16 = (ushort_t*)take((size_t)B_ * 256 * 2);
  float* sums = (float*)take(8);
  int* bar = (int*)take(4);
  int* gen = (int*)take(4);
  int* flg = (int*)take(4 * 2 * 32 * 64);   // one 64B line per flag
  size_t zero_bytes = o;
  // ---- write-once h ring: 3 layers x 129 slots x [B,U] bf16 (~97MB) ----
  ushort_t* ring = (ushort_t*)take(3 * LS_ * 2);
  // ---- recomputed-per-call region ----
  ushort_t* swz = (ushort_t*)take((size_t)1412096 * 16);
  float* tabE = (float*)take((size_t)V_ * G4_ * 4);
  float* tabD = (float*)take((size_t)V_ * G4_ * 4);

  hipMemsetAsync(wsb, 0, zero_bytes, stream);
  // zero slot 0 (t = -1 initial state) of each layer ring
  for (int l = 0; l < 3; l++)
    hipMemsetAsync(ring + (size_t)l * LS_, 0, SLOT_ * 2, stream);

  table_kernel<<<V_, 256, 0, stream>>>(emb_enc, enc_k0, 0, tabE);
  table_kernel<<<V_, 256, 0, stream>>>(emb_dec, dec_k0, 200, tabD);

  SwzSrc ss;
  ss.enc_rk0 = enc_rk0; ss.enc_k0 = enc_k0; ss.enc_b0 = enc_b0;
  ss.dec_rk0 = dec_rk0; ss.dec_k0 = dec_k0; ss.dec_b0 = dec_b0;
  ss.tabE = tabE; ss.tabD = tabD;
  ss.encK1 = enc_k1; ss.encR1 = enc_rk1; ss.encK2 = enc_k2; ss.encR2 = enc_rk2;
  ss.decK1 = dec_k1; ss.decR1 = dec_rk1; ss.decK2 = dec_k2; ss.decR2 = dec_rk2;
  ss.Wo = Wo; ss.dst = swz;
  swz_ext_kernel<<<1283, 256, 0, stream>>>(ss);

  PP pp;
  pp.swz = swz; pp.ring = ring;
  pp.c2g = c2g; pp.zf16 = zf16; pp.sums = sums; pp.bar = bar; pp.gen = gen; pp.flg = flg; pp.out = out;
  pp.enc_b1 = enc_b1; pp.enc_b2 = enc_b2; pp.dec_b1 = dec_b1; pp.dec_b2 = dec_b2;
  pp.Wm = Wm; pp.bm = bm; pp.Ws = Ws; pp.bs = bs; pp.eps = eps; pp.C = C; pp.bo = bo;
  pp.X = X; pp.Y = Y; pp.Lb = L;
  persist<<<NBLK, 256, 0, stream>>>(pp);
}

// Round 11
// 4996.594 us; speedup vs baseline: 1.0803x; 1.0803x over previous
//
#include <hip/hip_runtime.h>

#define B_ 256
#define T_ 128
#define V_ 42
#define LAT_ 200
#define U_ 512
#define G4_ 2048
#define NBLK 196
#define FI(r, m) ((((r) * 2) + (m)) * 32)
#define SLOT_ ((size_t)B_ * U_)          // 131072 ushorts per (layer,t) slot
#define LS_ ((size_t)129 * SLOT_)        // layer stride: 129 write-once slots

typedef unsigned short ushort_t;
typedef __attribute__((ext_vector_type(8))) short bf8;
typedef __attribute__((ext_vector_type(4))) float f4;

__device__ __forceinline__ ushort_t f2bf(float f) {
  union { float f; unsigned int i; } v; v.f = f;
  unsigned int r = v.i + 0x7fffu + ((v.i >> 16) & 1u);
  return (ushort_t)(r >> 16);
}
__device__ __forceinline__ float sigf(float x) { return 1.f / (1.f + __expf(-x)); }
__device__ __forceinline__ float tanhfast(float x) {
  float e = __expf(2.f * x);
  return 1.f - 2.f / (e + 1.f);
}
__device__ __forceinline__ void wait_vm0() {
  asm volatile("s_waitcnt vmcnt(0)" ::: "memory");
}
// ---- MALL-coherent write-through stores (R4/R7-proven) ----
__device__ __forceinline__ void st_wt_b16(void* p, ushort_t v) {
  unsigned int vv = v;
  asm volatile("global_store_short %0, %1, off sc0 sc1" :: "v"(p), "v"(vv) : "memory");
}
__device__ __forceinline__ void st_wt_b32(void* p, unsigned int v) {
  asm volatile("global_store_dword %0, %1, off sc0 sc1" :: "v"(p), "v"(v) : "memory");
}

// table[v][j] = sum_n emb[v,n] * k0[roff+n][j]
__global__ __launch_bounds__(256) void table_kernel(const float* emb, const float* k0, int roff, float* table) {
  int v = blockIdx.x, tid = threadIdx.x;
  __shared__ float e[LAT_];
  for (int i = tid; i < LAT_; i += 256) e[i] = emb[v * LAT_ + i];
  __syncthreads();
  for (int j = tid; j < G4_; j += 256) {
    float s = 0.f;
    for (int n = 0; n < LAT_; n++) s += e[n] * k0[(size_t)(roff + n) * G4_ + j];
    table[v * G4_ + j] = s;
  }
}

// ---------------------------------------------------------------------------
// Swizzled-weight layout per matrix: [nt16][kt][lane][8] bf16.
// Mats: 0=encL0ext(KT18) 1=decL0ext(KT26) 2..5=encK1,R1,K2,R2 6..9=dec...
// 10=Wo (3 nt16, KT16, 48 cols padded).
// ---------------------------------------------------------------------------
__device__ __forceinline__ size_t mat_off_u4(int m) {
  if (m == 0) return 0;
  if (m == 1) return 147456;
  if (m < 10) return 360448 + (size_t)(m - 2) * 131072;
  return 1409024;
}

struct SwzSrc {
  const float *enc_rk0, *enc_k0, *enc_b0;
  const float *dec_rk0, *dec_k0, *dec_b0;
  const float *tabE, *tabD;
  const float *encK1, *encR1, *encK2, *encR2;
  const float *decK1, *decR1, *decK2, *decR2;
  const float *Wo;
  ushort_t* dst;
};

__device__ float swz_val(const SwzSrc& s, int mat, int k, int n) {
  switch (mat) {
    case 0: {
      if (k < 512) return s.enc_rk0[(size_t)k * G4_ + n];
      int i = k - 512;
      if (i < 42) return s.tabE[(size_t)i * G4_ + n];
      if (i < 45) return s.enc_k0[(size_t)(200 + i - 42) * G4_ + n];
      if (i == 45) return s.enc_b0[n];
      return 0.f;
    }
    case 1: {
      if (k < 512) return s.dec_rk0[(size_t)k * G4_ + n];
      int i = k - 512;
      if (i < 200) return s.dec_k0[(size_t)i * G4_ + n];
      if (i < 256) return 0.f;
      i -= 256;
      if (i < 42) return s.tabD[(size_t)i * G4_ + n];
      if (i < 45) return s.dec_k0[(size_t)(400 + i - 42) * G4_ + n];
      if (i == 45) return s.dec_b0[n];
      return 0.f;
    }
    case 2: return s.encK1[(size_t)k * G4_ + n];
    case 3: return s.encR1[(size_t)k * G4_ + n];
    case 4: return s.encK2[(size_t)k * G4_ + n];
    case 5: return s.encR2[(size_t)k * G4_ + n];
    case 6: return s.decK1[(size_t)k * G4_ + n];
    case 7: return s.decR1[(size_t)k * G4_ + n];
    case 8: return s.decK2[(size_t)k * G4_ + n];
    case 9: return s.decR2[(size_t)k * G4_ + n];
    default: return (n < V_) ? s.Wo[(size_t)k * V_ + n] : 0.f;
  }
}

__global__ __launch_bounds__(256) void swz_ext_kernel(SwzSrc s) {
  int b = blockIdx.x, tid = threadIdx.x;
  int mat, nt16;
  if (b < 1280) { mat = b >> 7; nt16 = b & 127; } else { mat = 10; nt16 = b - 1280; }
  int ktMax = (mat == 0) ? 18 : (mat == 1) ? 26 : 16;
  int lane = tid & 63, l15 = lane & 15, q = lane >> 4;
  int n = nt16 * 16 + l15;
  uint4* dst = (uint4*)s.dst;
  size_t off = mat_off_u4(mat);
  for (int kt = tid >> 6; kt < ktMax; kt += 4) {
    ushort_t o[8];
    int kb = kt * 32 + q * 8;
#pragma unroll
    for (int j = 0; j < 8; j++) o[j] = f2bf(swz_val(s, mat, kb + j, n));
    dst[off + ((size_t)nt16 * ktMax + kt) * 64 + lane] = *(const uint4*)o;
  }
}

// ---------------------------------------------------------------------------
struct PP {
  const ushort_t* swz;
  ushort_t* ring;                 // write-once h: [3 layers][129 slots][B][U] bf16
  float* c2g; ushort_t* zf16; float* sums; int* bar; int* gen; int* flg; float* out;
  const float *enc_b1, *enc_b2, *dec_b1, *dec_b2;
  const float *Wm, *bm, *Ws, *bs, *eps, *C, *bo;
  const int *X, *Y, *Lb;
};

// Full grid barrier — phase boundaries only. All-thread rel/acq fences.
__device__ __forceinline__ void grid_barrier(int* bar, int* gen) {
  __builtin_amdgcn_fence(__ATOMIC_RELEASE, "agent");
  __syncthreads();
  if (threadIdx.x == 0) {
    int g = __hip_atomic_load(gen, __ATOMIC_RELAXED, __HIP_MEMORY_SCOPE_AGENT);
    if (__hip_atomic_fetch_add(bar, 1, __ATOMIC_ACQ_REL, __HIP_MEMORY_SCOPE_AGENT) == NBLK - 1) {
      __hip_atomic_store(bar, 0, __ATOMIC_RELAXED, __HIP_MEMORY_SCOPE_AGENT);
      __hip_atomic_store(gen, g + 1, __ATOMIC_RELEASE, __HIP_MEMORY_SCOPE_AGENT);
    } else {
      int gg;
      do {
        __builtin_amdgcn_s_sleep(1);
        gg = __hip_atomic_load(gen, __ATOMIC_ACQUIRE, __HIP_MEMORY_SCOPE_AGENT);
      } while (gg == g);
    }
  }
  __syncthreads();
  __builtin_amdgcn_fence(__ATOMIC_ACQUIRE, "agent");
}

#define MFMA(a, bfrag, c) __builtin_amdgcn_mfma_f32_16x16x32_bf16((a), (bfrag), (c), 0, 0, 0)

// Hot poll + MFMA burn: keeps the matrix pipe busy while waiting so DPM
// does not clock the chip down (theory: ~4-5x latency inflation at idle).
__device__ __forceinline__ void wait_flags(const int* f, int cnt, int target, f4* junk, bf8 ja) {
  int lane = threadIdx.x & 63;
  const int* a = f + (lane < cnt ? lane : 0);
  for (;;) {
    int v = __hip_atomic_load(a, __ATOMIC_RELAXED, __HIP_MEMORY_SCOPE_AGENT);
    bool bad = (lane < cnt) && (v < target);
    if (__ballot(bad) == 0ull) return;
#pragma unroll
    for (int i = 0; i < 8; i++) *junk = MFMA(ja, ja, *junk);
  }
}

__global__ __launch_bounds__(256, 1) void persist(PP p) {
  __shared__ uint4 wlds4[8192];  // 128KB: weights + z-scratch + token caches
  const int b = blockIdx.x, tid = threadIdx.x;
  const int lane = tid & 63, w = tid >> 6, q = lane >> 4, l15 = lane & 15;
  const int role = b < 64 ? 0 : b < 128 ? 1 : b < 192 ? 2 : 3;
  const int idx = b & 63;
  const int ut = idx >> 1;
  const int mi = idx & 1;
  const int m0 = mi * 128;
  const int rw = m0 + w * 32;
  const int u = ut * 16 + l15;
  const uint4* swzU4 = (const uint4*)p.swz;
  const int cb = b - 192;

  unsigned char* tok = (unsigned char*)wlds4 + 106496;  // role0 X cache [128][133]
  unsigned char* ytok = (unsigned char*)wlds4 + 49152;  // CE Y cache [64][133]

  // DPM-burn state (never observable: sink is data-dependent never-true)
  f4 junk = {0.f, 0.f, 0.f, 0.f};
  bf8 ja = {0, 0, 0, 0, 0, 0, 0, 0};

  // layer-0 per-lane constants: C rows as bf16
  ushort_t cb0[2][3];
  if (role == 0) {
#pragma unroll
    for (int ms = 0; ms < 2; ms++)
#pragma unroll
      for (int j = 0; j < 3; j++) cb0[ms][j] = f2bf(p.C[(rw + ms * 16 + l15) * 3 + j]);
  }

  const int pubidx = FI(role, mi) + ut;  // role<3 only

  float ce_local = 0.f;
  float boR0 = 0.f, boR1 = 0.f, boR2 = 0.f;
  int Lr[4] = {0, 0, 0, 0};
  int pub = 0;

  for (int phase = 0; phase < 2; phase++) {
    const bool dec = (phase == 1);

    if (dec) {
      grid_barrier(p.bar, p.gen);  // encoder fully done; c2g visible; ring lines invalidated
      if (b < 50) {
        // ---- VAE (blocks 0..49): z + KL ----
        int lat0 = b * 4;
        int row = tid;
        float m[4], ls[4];
#pragma unroll
        for (int lc = 0; lc < 4; lc++) { m[lc] = p.bm[lat0 + lc]; ls[lc] = p.bs[lat0 + lc]; }
        const float* cr = p.c2g + (size_t)row * U_;
        for (int k = 0; k < U_; k++) {
          float hv = cr[k];
#pragma unroll
          for (int lc = 0; lc < 4; lc++) {
            m[lc] += hv * p.Wm[k * LAT_ + lat0 + lc];
            ls[lc] += hv * p.Ws[k * LAT_ + lat0 + lc];
          }
        }
        float kl = 0.f;
#pragma unroll
        for (int lc = 0; lc < 4; lc++) {
          int lat = lat0 + lc;
          float zz = m[lc] + __expf(0.5f * ls[lc]) * p.eps[row * LAT_ + lat];
          p.zf16[row * 256 + lat] = f2bf(zz);
          kl += 1.f + ls[lc] - m[lc] * m[lc] - __expf(ls[lc]);
        }
        float* red = (float*)wlds4;
        red[tid] = kl; __syncthreads();
        for (int st = 128; st > 0; st >>= 1) { if (tid < st) red[tid] += red[tid + st]; __syncthreads(); }
        if (tid == 0) atomicAdd(p.sums + 1, red[0]);
      }
      __syncthreads();
    }

    // ---- stage weights (+ token caches) for this phase into LDS ----
    // role0 step layout (both phases): [g][kt 0..17][lane] with kt16..17 = const region.
    // decoder additionally stages z-weights (src kt16..23) at z-scratch u4[4608..6656).
    if (role == 0) {
      if (!dec) {
        size_t mo = mat_off_u4(0);
        for (int g = 0; g < 4; g++) {
          int nt16 = g * 32 + ut;
          size_t src = mo + (size_t)nt16 * 18 * 64;
          int dst = g * 18 * 64;
          for (int i = tid; i < 18 * 64; i += 256) wlds4[dst + i] = swzU4[src + i];
        }
        // X token cache (persists through both phases)
        for (int i = tid; i < 128 * T_; i += 256) {
          int r = i >> 7, t = i & 127;
          tok[r * 133 + t] = (unsigned char)p.X[(size_t)(m0 + r) * T_ + t];
        }
      } else {
        size_t mo = mat_off_u4(1);  // KT26 source layout
        for (int g = 0; g < 4; g++) {
          int nt16 = g * 32 + ut;
          size_t src = mo + (size_t)nt16 * 26 * 64;
          int dst = g * 18 * 64;
          for (int i = tid; i < 16 * 64; i += 256) wlds4[dst + i] = swzU4[src + i];               // rk0
          for (int i = tid; i < 2 * 64; i += 256) wlds4[dst + 16 * 64 + i] = swzU4[src + 24 * 64 + i];  // const
          for (int i = tid; i < 8 * 64; i += 256) wlds4[4608 + g * 512 + i] = swzU4[src + 16 * 64 + i]; // z
        }
      }
    } else if (role <= 2) {
      int matK = dec ? (role == 1 ? 6 : 8) : (role == 1 ? 2 : 4);
      for (int gm = 0; gm < 2; gm++) {
        size_t mo = mat_off_u4(matK + gm);
        for (int g = 0; g < 4; g++) {
          int nt16 = g * 32 + ut;
          size_t src = mo + (size_t)nt16 * 1024;
          int dst = gm * 4096 + g * 1024;
          for (int i = tid; i < 1024; i += 256) wlds4[dst + i] = swzU4[src + i];
        }
      }
    } else if (dec) {
      size_t mo = mat_off_u4(10);
      for (int i = tid; i < 3072; i += 256) wlds4[i] = swzU4[mo + i];
      for (int i = tid; i < 64 * T_; i += 256) {
        int r = i >> 7, t = i & 127;
        ytok[r * 133 + t] = (unsigned char)p.Y[(size_t)(cb * 64 + r) * T_ + t];
      }
      int r0c = cb * 64 + w * 16;
      boR0 = p.bo[l15]; boR1 = p.bo[16 + l15]; boR2 = (l15 < 10) ? p.bo[32 + l15] : 0.f;
#pragma unroll
      for (int r = 0; r < 4; r++) Lr[r] = p.Lb[r0c + q * 4 + r];
    }
    __syncthreads();

    // ---- per-phase register state ----
    float creg[2][4];
#pragma unroll
    for (int ms = 0; ms < 2; ms++)
#pragma unroll
      for (int r = 0; r < 4; r++) creg[ms][r] = 0.f;
    float bias[4] = {0.f, 0.f, 0.f, 0.f};
    if (role == 1 || role == 2) {
      const float* bb = dec ? (role == 1 ? p.dec_b1 : p.dec_b2) : (role == 1 ? p.enc_b1 : p.enc_b2);
#pragma unroll
      for (int g = 0; g < 4; g++) bias[g] = bb[g * 512 + u];
    }

    // ---- wait-sets (write-once ring: RAW deps only, no WAR).
    //      role3 now paces (and burns) in BOTH phases to keep its CU hot. ----
    const int* myp = nullptr; int myc = 0;
    if (role == 0) {
      if (w == 0) { myp = p.flg + FI(0, mi); myc = 32; }
    } else if (role == 1) {
      if (w == 0) { myp = p.flg + FI(0, mi); myc = 32; }
      else if (w == 1) { myp = p.flg + FI(1, mi); myc = 32; }
    } else if (role == 2) {
      if (w == 0) { myp = p.flg + FI(1, mi); myc = 32; }
      else if (w == 1) { myp = p.flg + FI(2, mi); myc = 32; }
    } else {
      if (w == 0) { myp = p.flg + FI(2, cb >> 1); myc = 32; }
    }

    grid_barrier(p.bar, p.gen);  // phase aligned; zf16/weights visible

    // ---- per-phase accumulator init (zacc): decoder role0 folds the constant
    //      z-contribution here ONCE (8-kt MFMA vs z-scratch); else zero. ----
    f4 zacc[2][4];
#pragma unroll
    for (int ms = 0; ms < 2; ms++)
#pragma unroll
      for (int g = 0; g < 4; g++) zacc[ms][g] = (f4){0.f, 0.f, 0.f, 0.f};
    if (role == 0 && dec) {
      const ushort_t* Az0 = p.zf16 + (rw + l15) * 256 + q * 8;
#pragma unroll
      for (int kz = 0; kz < 8; kz++) {
        bf8 a0 = *(const bf8*)(Az0 + kz * 32);
        bf8 a1 = *(const bf8*)(Az0 + 16 * 256 + kz * 32);
#pragma unroll
        for (int g = 0; g < 4; g++) {
          bf8 bbf = *(const bf8*)&wlds4[4608 + g * 512 + kz * 64 + lane];
          zacc[0][g] = MFMA(a0, bbf, zacc[0][g]);
          zacc[1][g] = MFMA(a1, bbf, zacc[1][g]);
        }
      }
    }

    // ---- wavefront steps: flag-synced, fence-free, write-once slots ----
    const int smax = dec ? T_ + 3 : T_ + 2;
    for (int s = 0; s < smax; s++) {
      pub++;
      if (myc) wait_flags(myp, myc, pub - 1, &junk, ja);
      __syncthreads();

      const int lag = (role <= 2) ? role : 3;
      const int t = s - lag;
      if (role == 3) {
        if (dec && t >= 0 && t < T_) {
          // ======== CE: logits GEMM + online softmax (h2[t] at slot t+1) ========
          int r0c = cb * 64 + w * 16;
          const ushort_t* Ar = p.ring + 2 * LS_ + (size_t)(t + 1) * SLOT_ + (size_t)(r0c + l15) * U_ + q * 8;
          f4 a3[3];
#pragma unroll
          for (int nt = 0; nt < 3; nt++) a3[nt] = (f4){0.f, 0.f, 0.f, 0.f};
#pragma unroll 4
          for (int kt = 0; kt < 16; kt++) {
            bf8 a = *(const bf8*)(Ar + kt * 32);
#pragma unroll
            for (int nt = 0; nt < 3; nt++) {
              bf8 bbf = *(const bf8*)&wlds4[nt * 1024 + kt * 64 + lane];
              a3[nt] = MFMA(a, bbf, a3[nt]);
            }
          }
#pragma unroll
          for (int r = 0; r < 4; r++) {
            float v0 = a3[0][r] + boR0;
            float v1 = a3[1][r] + boR1;
            float v2 = (l15 < 10) ? a3[2][r] + boR2 : -3.0e38f;
            float mx = fmaxf(fmaxf(v0, v1), v2);
            mx = fmaxf(mx, __shfl_xor(mx, 1)); mx = fmaxf(mx, __shfl_xor(mx, 2));
            mx = fmaxf(mx, __shfl_xor(mx, 4)); mx = fmaxf(mx, __shfl_xor(mx, 8));
            float se = __expf(v0 - mx) + __expf(v1 - mx) + ((l15 < 10) ? __expf(v2 - mx) : 0.f);
            int yv = ytok[(w * 16 + q * 4 + r) * 133 + t];
            float py = (l15 == yv ? v0 : 0.f) + (l15 + 16 == yv ? v1 : 0.f) + (l15 + 32 == yv ? v2 : 0.f);
            se += __shfl_xor(se, 1); se += __shfl_xor(se, 2); se += __shfl_xor(se, 4); se += __shfl_xor(se, 8);
            py += __shfl_xor(py, 1); py += __shfl_xor(py, 2); py += __shfl_xor(py, 4); py += __shfl_xor(py, 8);
            if (l15 == 0 && t < Lr[r]) ce_local += mx + __logf(se) - py;
          }
        }
      } else if (t >= 0 && t < T_) {
        // ======== LSTM layer step ========
        f4 acc[2][4];
#pragma unroll
        for (int ms = 0; ms < 2; ms++)
#pragma unroll
          for (int g = 0; g < 4; g++) acc[ms][g] = zacc[ms][g];

        const ushort_t* hin = p.ring + (size_t)role * LS_ + (size_t)t * SLOT_;        // h[t-1]
        ushort_t* hout = p.ring + (size_t)role * LS_ + (size_t)(t + 1) * SLOT_;       // h[t]
        const ushort_t* Ah0 = hin + (size_t)(rw + l15) * U_ + q * 8;
        const ushort_t* Ah1 = Ah0 + 16 * U_;

        if (role == 0) {
          const int KT64 = 18 * 64;
#pragma unroll 4
          for (int kt = 0; kt < 16; kt++) {
            bf8 a0 = *(const bf8*)(Ah0 + kt * 32);
            bf8 a1 = *(const bf8*)(Ah1 + kt * 32);
#pragma unroll
            for (int g = 0; g < 4; g++) {
              bf8 bbf = *(const bf8*)&wlds4[g * KT64 + kt * 64 + lane];
              acc[0][g] = MFMA(a0, bbf, acc[0][g]);
              acc[1][g] = MFMA(a1, bbf, acc[1][g]);
            }
          }
          // const region at kt 16..17 (one-hot token, C, 1)
          int xv0 = tok[(w * 32 + l15) * 133 + t];
          int xv1 = tok[(w * 32 + 16 + l15) * 133 + t];
#pragma unroll
          for (int ktc = 0; ktc < 2; ktc++) {
            union { ushort_t us[8]; bf8 v; } a0u, a1u;
#pragma unroll
            for (int j = 0; j < 8; j++) {
              int id = ktc * 32 + q * 8 + j;
              ushort_t v0 = (id == xv0) ? (ushort_t)0x3F80 : (ushort_t)0;
              ushort_t v1 = (id == xv1) ? (ushort_t)0x3F80 : (ushort_t)0;
              if (id >= 42 && id < 45) { v0 = cb0[0][id - 42]; v1 = cb0[1][id - 42]; }
              if (id == 45) { v0 = 0x3F80; v1 = 0x3F80; }
              a0u.us[j] = v0; a1u.us[j] = v1;
            }
            int kt = 16 + ktc;
#pragma unroll
            for (int g = 0; g < 4; g++) {
              bf8 bbf = *(const bf8*)&wlds4[g * KT64 + kt * 64 + lane];
              acc[0][g] = MFMA(a0u.v, bbf, acc[0][g]);
              acc[1][g] = MFMA(a1u.v, bbf, acc[1][g]);
            }
          }
        } else {
          const ushort_t* xin = p.ring + (size_t)(role - 1) * LS_ + (size_t)(t + 1) * SLOT_;  // h^{l-1}[t]
          const ushort_t* Ax0 = xin + (size_t)(rw + l15) * U_ + q * 8;
          const ushort_t* Ax1 = Ax0 + 16 * U_;
#pragma unroll 4
          for (int kt = 0; kt < 16; kt++) {
            bf8 a0 = *(const bf8*)(Ax0 + kt * 32);
            bf8 a1 = *(const bf8*)(Ax1 + kt * 32);
#pragma unroll
            for (int g = 0; g < 4; g++) {
              bf8 bbf = *(const bf8*)&wlds4[g * 1024 + kt * 64 + lane];
              acc[0][g] = MFMA(a0, bbf, acc[0][g]);
              acc[1][g] = MFMA(a1, bbf, acc[1][g]);
            }
          }
#pragma unroll 4
          for (int kt = 0; kt < 16; kt++) {
            bf8 a0 = *(const bf8*)(Ah0 + kt * 32);
            bf8 a1 = *(const bf8*)(Ah1 + kt * 32);
#pragma unroll
            for (int g = 0; g < 4; g++) {
              bf8 bbf = *(const bf8*)&wlds4[4096 + g * 1024 + kt * 64 + lane];
              acc[0][g] = MFMA(a0, bbf, acc[0][g]);
              acc[1][g] = MFMA(a1, bbf, acc[1][g]);
            }
          }
        }

        // ---- gate pointwise; h stores write-through sc0 sc1 ----
#pragma unroll
        for (int ms = 0; ms < 2; ms++)
#pragma unroll
          for (int r = 0; r < 4; r++) {
            int row = rw + ms * 16 + q * 4 + r;
            float zi = acc[ms][0][r] + bias[0];
            float zf = acc[ms][1][r] + bias[1];
            float zg = acc[ms][2][r] + bias[2];
            float zo = acc[ms][3][r] + bias[3];
            float cp = creg[ms][r];
            float cn = sigf(zf) * cp + sigf(zi) * tanhfast(zg);
            float hn = sigf(zo) * tanhfast(cn);
            creg[ms][r] = cn;
            st_wt_b16(&hout[(size_t)row * U_ + u], f2bf(hn));
            if (!dec && role == 2 && t == T_ - 1) p.c2g[(size_t)row * U_ + u] = cn;
          }
      }
      wait_vm0();        // all h stores ACKed at the MALL
      __syncthreads();   // ... for every wave of the block
      if (tid == 0 && role < 3) st_wt_b32(p.flg + pubidx, (unsigned int)pub);
    }
  }

  // ---- never-true sink keeps the burn MFMAs live ----
  if (p.X[0] == 0x12345678 && tid == 0) atomicAdd(p.out, junk[0]);

  // ---- CE flush, final reduce ----
  if (role == 3 && l15 == 0) atomicAdd(p.sums + 0, ce_local);
  grid_barrier(p.bar, p.gen);
  if (b == 0 && tid == 0) {
    float recon = p.sums[0] * (1.f / ((float)B_ * (float)T_));
    float latent = -0.5f * p.sums[1] * (1.f / ((float)B_ * (float)LAT_));
    p.out[0] = recon + latent;
    p.out[1] = recon;
    p.out[2] = latent;
  }
}

// ---------------------------------------------------------------------------
extern "C" void kernel_launch(void* const* d_in, const int* in_sizes, int n_in,
                              void* d_out, int out_size, void* d_ws, size_t ws_size,
                              hipStream_t stream) {
  const int*   X       = (const int*)d_in[0];
  const int*   Y       = (const int*)d_in[1];
  const float* C       = (const float*)d_in[2];
  const int*   L       = (const int*)d_in[3];
  const float* eps     = (const float*)d_in[4];
  const float* emb_enc = (const float*)d_in[5];
  const float* emb_dec = (const float*)d_in[6];
  const float* enc_k0  = (const float*)d_in[7];
  const float* enc_rk0 = (const float*)d_in[8];
  const float* enc_b0  = (const float*)d_in[9];
  const float* enc_k1  = (const float*)d_in[10];
  const float* enc_rk1 = (const float*)d_in[11];
  const float* enc_b1  = (const float*)d_in[12];
  const float* enc_k2  = (const float*)d_in[13];
  const float* enc_rk2 = (const float*)d_in[14];
  const float* enc_b2  = (const float*)d_in[15];
  const float* dec_k0  = (const float*)d_in[16];
  const float* dec_rk0 = (const float*)d_in[17];
  const float* dec_b0  = (const float*)d_in[18];
  const float* dec_k1  = (const float*)d_in[19];
  const float* dec_rk1 = (const float*)d_in[20];
  const float* dec_b1  = (const float*)d_in[21];
  const float* dec_k2  = (const float*)d_in[22];
  const float* dec_rk2 = (const float*)d_in[23];
  const float* dec_b2  = (const float*)d_in[24];
  const float* Wm      = (const float*)d_in[25];
  const float* bm      = (const float*)d_in[26];
  const float* Ws      = (const float*)d_in[27];
  const float* bs      = (const float*)d_in[28];
  const float* Wo      = (const float*)d_in[29];
  const float* bo      = (const float*)d_in[30];
  float* out = (float*)d_out;
  (void)in_sizes; (void)n_in; (void)out_size; (void)ws_size;

  char* wsb = (char*)d_ws;
  size_t o = 0;
  auto take = [&](size_t bytes) -> char* { char* p = wsb + o; o += (bytes + 255) & ~(size_t)255; return p; };

  // ---- small zeroed region ----
  float* c2g  = (float*)take((size_t)B_ * U_ * 4);
  ushort_t* zf16 = (ushort_t*)take((size_t)B_ * 256 * 2);
  float* sums = (float*)take(8);
  int* bar = (int*)take(4);
  int* gen = (int*)take(4);
  int* flg = (int*)take(4 * 2 * 32 * 4);
  size_t zero_bytes = o;
  // ---- write-once h ring: 3 layers x 129 slots x [B,U] bf16 (~97MB) ----
  ushort_t* ring = (ushort_t*)take(3 * LS_ * 2);
  // ---- recomputed-per-call region ----
  ushort_t* swz = (ushort_t*)take((size_t)1412096 * 16);
  float* tabE = (float*)take((size_t)V_ * G4_ * 4);
  float* tabD = (float*)take((size_t)V_ * G4_ * 4);

  hipMemsetAsync(wsb, 0, zero_bytes, stream);
  // zero slot 0 (t = -1 initial state) of each layer ring
  for (int l = 0; l < 3; l++)
    hipMemsetAsync(ring + (size_t)l * LS_, 0, SLOT_ * 2, stream);

  table_kernel<<<V_, 256, 0, stream>>>(emb_enc, enc_k0, 0, tabE);
  table_kernel<<<V_, 256, 0, stream>>>(emb_dec, dec_k0, 200, tabD);

  SwzSrc ss;
  ss.enc_rk0 = enc_rk0; ss.enc_k0 = enc_k0; ss.enc_b0 = enc_b0;
  ss.dec_rk0 = dec_rk0; ss.dec_k0 = dec_k0; ss.dec_b0 = dec_b0;
  ss.tabE = tabE; ss.tabD = tabD;
  ss.encK1 = enc_k1; ss.encR1 = enc_rk1; ss.encK2 = enc_k2; ss.encR2 = enc_rk2;
  ss.decK1 = dec_k1; ss.decR1 = dec_rk1; ss.decK2 = dec_k2; ss.decR2 = dec_rk2;
  ss.Wo = Wo; ss.dst = swz;
  swz_ext_kernel<<<1283, 256, 0, stream>>>(ss);

  PP pp;
  pp.swz = swz; pp.ring = ring;
  pp.c2g = c2g; pp.zf16 = zf16; pp.sums = sums; pp.bar = bar; pp.gen = gen; pp.flg = flg; pp.out = out;
  pp.enc_b1 = enc_b1; pp.enc_b2 = enc_b2; pp.dec_b1 = dec_b1; pp.dec_b2 = dec_b2;
  pp.Wm = Wm; pp.bm = bm; pp.Ws = Ws; pp.bs = bs; pp.eps = eps; pp.C = C; pp.bo = bo;
  pp.X = X; pp.Y = Y; pp.Lb = L;
  persist<<<NBLK, 256, 0, stream>>>(pp);
}